// Round 2
// baseline (1920.435 us; speedup 1.0000x reference)
//
#include <hip/hip_runtime.h>

#define DI __device__ __forceinline__

typedef __bf16 bf16x8 __attribute__((ext_vector_type(8)));
typedef float  f32x4  __attribute__((ext_vector_type(4)));

DI f32x4 splat4(float b) { f32x4 v; v[0] = b; v[1] = b; v[2] = b; v[3] = b; return v; }

// tanh-form GELU via sigmoid identity: gelu(x) = x / (1 + exp(-2u)), u = 0.79788456(x + 0.044715x^3)
DI float gelu_fast(float x) {
    float x3 = x * x * x;
    float z = -1.5957691216057308f * fmaf(0.044715f, x3, x);
    float e = __expf(z);
    return __fdividef(x, 1.0f + e);
}

// ---------------- prep: transpose weights to bf16 Bt[n][k] layouts ----------------
// ws elements (bf16): [0,12288) cons_W1t [384][32] (K padded 12->32)
//                     [12288,86016) cons_W2t [192][384]
//                     [86016,159744) out_W1t [384][192]
//                     [159744,233472) out_W2t [192][384]
__global__ void prep_w(const float* __restrict__ cW1, const float* __restrict__ cW2,
                       const float* __restrict__ oW1, const float* __restrict__ oW2,
                       __bf16* __restrict__ ws) {
    int id = blockIdx.x * 256 + threadIdx.x;
    if (id < 12288) {
        int n = id >> 5, k = id & 31;
        ws[id] = (k < 12) ? (__bf16)cW1[k * 384 + n] : (__bf16)0.0f;
    } else if (id < 86016) {
        int t = id - 12288;
        int n = t / 384, k = t % 384;
        ws[id] = (__bf16)cW2[k * 192 + n];
    } else if (id < 159744) {
        int t = id - 86016;
        int n = t / 192, k = t % 192;
        ws[id] = (__bf16)oW1[k * 384 + n];
    } else if (id < 233472) {
        int t = id - 159744;
        int n = t / 384, k = t % 384;
        ws[id] = (__bf16)oW2[k * 192 + n];
    }
}

// flag projection table: 128 combos x 192, exact erf GELU, f32
__global__ void prep_ft(const float* __restrict__ W1, const float* __restrict__ b1,
                        const float* __restrict__ W2, const float* __restrict__ b2,
                        float* __restrict__ ftab) {
    __shared__ float h[384];
    int c = blockIdx.x;
    int tid = threadIdx.x;  // 0..191
    #pragma unroll
    for (int half = 0; half < 2; ++half) {
        int j = tid + half * 192;
        float v = b1[j];
        #pragma unroll
        for (int i = 0; i < 7; ++i)
            if (c & (1 << i)) v += W1[i * 384 + j];
        h[j] = 0.5f * v * (1.0f + erff(v * 0.70710678118654752f));
    }
    __syncthreads();
    float acc = b2[tid];
    for (int j = 0; j < 384; ++j)
        acc += h[j] * W2[j * 192 + tid];
    ftab[c * 192 + tid] = acc;
}

// ---------------- fused main kernel ----------------
__global__ __launch_bounds__(256, 3) void me_main(
    const float* __restrict__ flags, const float* __restrict__ cons,
    const int* __restrict__ from_sq, const int* __restrict__ to_sq,
    const int* __restrict__ kind_id, const int* __restrict__ promo_id,
    const int* __restrict__ meta_id, const int* __restrict__ mover_idx,
    const int* __restrict__ target_idx,
    const float* __restrict__ gctx, const float* __restrict__ piece,
    const float* __restrict__ sqe, const float* __restrict__ kinde,
    const float* __restrict__ promoe, const float* __restrict__ metae,
    const float* __restrict__ cons_b1, const float* __restrict__ cons_b2,
    const float* __restrict__ ln_g, const float* __restrict__ ln_b,
    const float* __restrict__ out_b1, const float* __restrict__ out_b2,
    const __bf16* __restrict__ cW1t, const __bf16* __restrict__ cW2t,
    const __bf16* __restrict__ oW1t, const __bf16* __restrict__ oW2t,
    const float* __restrict__ ftab, float* __restrict__ out) {
    __shared__ __align__(16) char smem[49152];
    const int tid = threadIdx.x;
    const int wave = tid >> 6;
    const int lane = tid & 63;
    const int lg = lane >> 4;  // 0..3
    const int lr = lane & 15;  // 0..15
    char* lds = smem + wave * 12288;  // per-wave private 12KB, reused h1 -> x -> h2
    const int mb = blockIdx.x * 64 + wave * 16;

    // ---- Phase E: embedding gathers summed directly into MFMA C-layout regs
    // acc2[t][r] = tok at (row rm=lg*4+r i.e. move mb+rm, col n=16t+lr)
    f32x4 acc2[12];
    float basev[12];
    #pragma unroll
    for (int t = 0; t < 12; ++t) {
        int n = t * 16 + lr;
        basev[t] = gctx[n] + cons_b2[n];
    }
    #pragma unroll
    for (int r = 0; r < 4; ++r) {
        int M = mb + lg * 4 + r;
        const float* p0 = piece + mover_idx[M] * 192;
        const float* p1 = piece + target_idx[M] * 192;
        const float* p2 = sqe + from_sq[M] * 192;
        const float* p3 = sqe + to_sq[M] * 192;
        const float* p4 = kinde + kind_id[M] * 192;
        const float* p5 = promoe + promo_id[M] * 192;
        const float* p6 = metae + meta_id[M] * 192;
        int fc = 0;
        #pragma unroll
        for (int i = 0; i < 7; ++i) fc |= (flags[M * 7 + i] > 0.5f) ? (1 << i) : 0;
        const float* p7 = ftab + fc * 192;
        #pragma unroll
        for (int t = 0; t < 12; ++t) {
            int n = t * 16 + lr;
            acc2[t][r] = basev[t] + p0[n] + p1[n] + p2[n] + p3[n] + p4[n] + p5[n] + p6[n] + p7[n];
        }
    }

    // ---- Phase C1: h1 = gelu(cons @ W1 + b1) -> LDS bf16 [16][384] (swizzled)
    bf16x8 af;
    #pragma unroll
    for (int i = 0; i < 8; ++i) {
        int k = lg * 8 + i;
        float v = (k < 12) ? cons[(mb + lr) * 12 + k] : 0.0f;
        af[i] = (__bf16)v;
    }
    #pragma unroll
    for (int h = 0; h < 2; ++h) {  // split 24 tiles in halves to cap register pressure
        f32x4 acc1[12];
        #pragma unroll
        for (int t = 0; t < 12; ++t) {
            int tt = h * 12 + t;
            acc1[t] = splat4(cons_b1[tt * 16 + lr]);
            bf16x8 bf = *(const bf16x8*)(cW1t + (tt * 16 + lr) * 32 + lg * 8);
            acc1[t] = __builtin_amdgcn_mfma_f32_16x16x32_bf16(af, bf, acc1[t], 0, 0, 0);
        }
        #pragma unroll
        for (int t = 0; t < 12; ++t) {
            int tt = h * 12 + t;
            #pragma unroll
            for (int r = 0; r < 4; ++r) {
                int rm = lg * 4 + r;
                int n = tt * 16 + lr;
                float g = gelu_fast(acc1[t][r]);
                *(__bf16*)(lds + rm * 768 + ((2 * n) ^ ((rm & 7) << 4))) = (__bf16)g;
            }
        }
    }
    __syncthreads();

    // ---- Phase C2: tok += h1 @ cons_W2
    #pragma unroll
    for (int ks = 0; ks < 12; ++ks) {
        bf16x8 a = *(const bf16x8*)(lds + lr * 768 + ((ks * 64 + lg * 16) ^ ((lr & 7) << 4)));
        #pragma unroll
        for (int t = 0; t < 12; ++t) {
            bf16x8 bf = *(const bf16x8*)(cW2t + (t * 16 + lr) * 384 + ks * 32 + lg * 8);
            acc2[t] = __builtin_amdgcn_mfma_f32_16x16x32_bf16(a, bf, acc2[t], 0, 0, 0);
        }
    }

    // ---- LayerNorm (f32, in-register, 16-lane shfl reduce) -> x bf16 [16][192] in LDS
    __syncthreads();  // h1 reads complete before region reuse
    #pragma unroll
    for (int r = 0; r < 4; ++r) {
        float s = 0.f, s2 = 0.f;
        #pragma unroll
        for (int t = 0; t < 12; ++t) { float v = acc2[t][r]; s += v; s2 += v * v; }
        s += __shfl_xor(s, 1); s2 += __shfl_xor(s2, 1);
        s += __shfl_xor(s, 2); s2 += __shfl_xor(s2, 2);
        s += __shfl_xor(s, 4); s2 += __shfl_xor(s2, 4);
        s += __shfl_xor(s, 8); s2 += __shfl_xor(s2, 8);
        float mu = s * (1.0f / 192.0f);
        float var = s2 * (1.0f / 192.0f) - mu * mu;
        float inv = rsqrtf(var + 1e-5f);
        int rm = lg * 4 + r;
        #pragma unroll
        for (int t = 0; t < 12; ++t) {
            int n = t * 16 + lr;
            float xv = (acc2[t][r] - mu) * inv * ln_g[n] + ln_b[n];
            *(__bf16*)(lds + rm * 384 + ((2 * n) ^ ((rm & 7) << 4))) = (__bf16)xv;
        }
    }
    __syncthreads();

    // ---- Phase C3: h2 = gelu(x @ out_W1 + b1) -> LDS bf16 [16][384]
    f32x4 acc3[24];
    #pragma unroll
    for (int t = 0; t < 24; ++t) acc3[t] = splat4(out_b1[t * 16 + lr]);
    #pragma unroll
    for (int ks = 0; ks < 6; ++ks) {
        bf16x8 a = *(const bf16x8*)(lds + lr * 384 + ((ks * 64 + lg * 16) ^ ((lr & 7) << 4)));
        #pragma unroll
        for (int t = 0; t < 24; ++t) {
            bf16x8 bf = *(const bf16x8*)(oW1t + (t * 16 + lr) * 192 + ks * 32 + lg * 8);
            acc3[t] = __builtin_amdgcn_mfma_f32_16x16x32_bf16(a, bf, acc3[t], 0, 0, 0);
        }
    }
    __syncthreads();  // x reads complete before region reuse
    #pragma unroll
    for (int t = 0; t < 24; ++t) {
        #pragma unroll
        for (int r = 0; r < 4; ++r) {
            int rm = lg * 4 + r;
            int n = t * 16 + lr;
            float g = gelu_fast(acc3[t][r]);
            *(__bf16*)(lds + rm * 768 + ((2 * n) ^ ((rm & 7) << 4))) = (__bf16)g;
        }
    }
    __syncthreads();

    // ---- Phase C4: out = h2 @ out_W2 + b2
    f32x4 acc4[12];
    #pragma unroll
    for (int t = 0; t < 12; ++t) acc4[t] = splat4(out_b2[t * 16 + lr]);
    #pragma unroll
    for (int ks = 0; ks < 12; ++ks) {
        bf16x8 a = *(const bf16x8*)(lds + lr * 768 + ((ks * 64 + lg * 16) ^ ((lr & 7) << 4)));
        #pragma unroll
        for (int t = 0; t < 12; ++t) {
            bf16x8 bf = *(const bf16x8*)(oW2t + (t * 16 + lr) * 384 + ks * 32 + lg * 8);
            acc4[t] = __builtin_amdgcn_mfma_f32_16x16x32_bf16(a, bf, acc4[t], 0, 0, 0);
        }
    }
    #pragma unroll
    for (int t = 0; t < 12; ++t) {
        #pragma unroll
        for (int r = 0; r < 4; ++r) {
            out[(mb + lg * 4 + r) * 192 + t * 16 + lr] = acc4[t][r];
        }
    }
}

extern "C" void kernel_launch(void* const* d_in, const int* in_sizes, int n_in,
                              void* d_out, int out_size, void* d_ws, size_t ws_size,
                              hipStream_t stream) {
    const float* flags  = (const float*)d_in[0];
    const float* cons   = (const float*)d_in[1];
    const int* from_sq  = (const int*)d_in[2];
    const int* to_sq    = (const int*)d_in[3];
    const int* kind_id  = (const int*)d_in[4];
    const int* promo_id = (const int*)d_in[5];
    const int* meta_id  = (const int*)d_in[6];
    const int* mover    = (const int*)d_in[7];
    const int* target   = (const int*)d_in[8];
    const float* gctx   = (const float*)d_in[9];
    const float* piece  = (const float*)d_in[10];
    const float* sqe    = (const float*)d_in[11];
    const float* kinde  = (const float*)d_in[12];
    const float* promoe = (const float*)d_in[13];
    const float* metae  = (const float*)d_in[14];
    const float* fW1    = (const float*)d_in[15];
    const float* fb1    = (const float*)d_in[16];
    const float* fW2    = (const float*)d_in[17];
    const float* fb2    = (const float*)d_in[18];
    const float* cW1    = (const float*)d_in[19];
    const float* cb1    = (const float*)d_in[20];
    const float* cW2    = (const float*)d_in[21];
    const float* cb2    = (const float*)d_in[22];
    const float* lng    = (const float*)d_in[23];
    const float* lnb    = (const float*)d_in[24];
    const float* oW1    = (const float*)d_in[25];
    const float* ob1    = (const float*)d_in[26];
    const float* oW2    = (const float*)d_in[27];
    const float* ob2    = (const float*)d_in[28];
    float* out = (float*)d_out;
    int N = in_sizes[2];

    __bf16* ws = (__bf16*)d_ws;
    const __bf16* cW1t = ws;
    const __bf16* cW2t = ws + 12288;
    const __bf16* oW1t = ws + 86016;
    const __bf16* oW2t = ws + 159744;
    float* ftab = (float*)(ws + 233472);

    prep_w<<<912, 256, 0, stream>>>(cW1, cW2, oW1, oW2, ws);
    prep_ft<<<128, 192, 0, stream>>>(fW1, fb1, fW2, fb2, ftab);
    me_main<<<N / 64, 256, 0, stream>>>(flags, cons, from_sq, to_sq, kind_id, promo_id,
                                        meta_id, mover, target, gctx, piece, sqe, kinde,
                                        promoe, metae, cb1, cb2, lng, lnb, ob1, ob2,
                                        cW1t, cW2t, oW1t, oW2t, ftab, out);
}

// Round 3
// 1222.725 us; speedup vs baseline: 1.5706x; 1.5706x over previous
//
#include <hip/hip_runtime.h>

#define DI __device__ __forceinline__

typedef __bf16 bf16x8 __attribute__((ext_vector_type(8)));
typedef float  f32x4  __attribute__((ext_vector_type(4)));
typedef float  f32x2  __attribute__((ext_vector_type(2)));

DI f32x4 splat4(float b) { f32x4 v; v[0] = b; v[1] = b; v[2] = b; v[3] = b; return v; }

// tanh-form GELU: gelu(x) = x / (1 + exp(-2u)), u = 0.79788456(x + 0.044715x^3)
DI float gelu_fast(float x) {
    float x3 = x * x * x;
    float z = -1.5957691216057308f * fmaf(0.044715f, x3, x);
    float e = __expf(z);
    return __fdividef(x, 1.0f + e);
}

// ---------------- prep: transpose weights to bf16 Bt[n][k] layouts ----------------
// ws (bf16 units): [0,12288) cons_W1t [384][32] (K padded 12->32)
//                  [12288,86016) cons_W2t [192][384]
//                  [86016,159744) out_W1t [384][192]
//                  [159744,233472) out_W2t [192][384]
// then ftab f32[128*192] at bf16-offset 233472 (byte 466944)
// then packed uint2[N] at byte 860160
__global__ void prep_w(const float* __restrict__ cW1, const float* __restrict__ cW2,
                       const float* __restrict__ oW1, const float* __restrict__ oW2,
                       __bf16* __restrict__ ws) {
    int id = blockIdx.x * 256 + threadIdx.x;
    if (id < 12288) {
        int n = id >> 5, k = id & 31;
        ws[id] = (k < 12) ? (__bf16)cW1[k * 384 + n] : (__bf16)0.0f;
    } else if (id < 86016) {
        int t = id - 12288;
        int n = t / 384, k = t % 384;
        ws[id] = (__bf16)cW2[k * 192 + n];
    } else if (id < 159744) {
        int t = id - 86016;
        int n = t / 192, k = t % 192;
        ws[id] = (__bf16)oW1[k * 384 + n];
    } else if (id < 233472) {
        int t = id - 159744;
        int n = t / 384, k = t % 384;
        ws[id] = (__bf16)oW2[k * 192 + n];
    }
}

// flag projection table: 128 combos x 192, exact erf GELU, f32
__global__ void prep_ft(const float* __restrict__ W1, const float* __restrict__ b1,
                        const float* __restrict__ W2, const float* __restrict__ b2,
                        float* __restrict__ ftab) {
    __shared__ float h[384];
    int c = blockIdx.x;
    int tid = threadIdx.x;  // 0..191
    #pragma unroll
    for (int half = 0; half < 2; ++half) {
        int j = tid + half * 192;
        float v = b1[j];
        #pragma unroll
        for (int i = 0; i < 7; ++i)
            if (c & (1 << i)) v += W1[i * 384 + j];
        h[j] = 0.5f * v * (1.0f + erff(v * 0.70710678118654752f));
    }
    __syncthreads();
    float acc = b2[tid];
    for (int j = 0; j < 384; ++j)
        acc += h[j] * W2[j * 192 + tid];
    ftab[c * 192 + tid] = acc;
}

// pack 6 indices + flag-code into one uint2 per move
__global__ void prep_pack(const float* __restrict__ flags,
                          const int* __restrict__ from_sq, const int* __restrict__ to_sq,
                          const int* __restrict__ kind_id, const int* __restrict__ promo_id,
                          const int* __restrict__ meta_id, const int* __restrict__ mover,
                          const int* __restrict__ target, uint2* __restrict__ pk, int N) {
    int t = blockIdx.x * 256 + threadIdx.x;
    if (t >= N) return;
    unsigned fc = 0;
    #pragma unroll
    for (int i = 0; i < 7; ++i) fc |= (flags[t * 7 + i] > 0.5f) ? (1u << i) : 0u;
    unsigned a = (unsigned)mover[t] | ((unsigned)target[t] << 8) |
                 ((unsigned)from_sq[t] << 16) | ((unsigned)to_sq[t] << 24);
    unsigned b = (unsigned)kind_id[t] | ((unsigned)promo_id[t] << 8) |
                 ((unsigned)meta_id[t] << 16) | (fc << 24);
    uint2 v; v.x = a; v.y = b;
    pk[t] = v;
}

// ---------------- fused main kernel: 4 waves cooperate on 64 moves ----------------
// wave w owns output/h-cols slice; intermediates shared in LDS.
// LDS: [0,24576) region A: h1 rows 0..31, later x[64][192] bf16
//      [24576,49152) region B: h1 rows 32..63, later h2-half [64][192] bf16
//      [49152,51200) region P: LN partials [64 rows][4 waves][2] f32
__global__ __launch_bounds__(256, 3) void me_main(
    const float* __restrict__ cons, const uint2* __restrict__ pk,
    const float* __restrict__ gctx, const float* __restrict__ piece,
    const float* __restrict__ sqe, const float* __restrict__ kinde,
    const float* __restrict__ promoe, const float* __restrict__ metae,
    const float* __restrict__ cons_b1, const float* __restrict__ cons_b2,
    const float* __restrict__ ln_g, const float* __restrict__ ln_b,
    const float* __restrict__ out_b1, const float* __restrict__ out_b2,
    const __bf16* __restrict__ cW1t, const __bf16* __restrict__ cW2t,
    const __bf16* __restrict__ oW1t, const __bf16* __restrict__ oW2t,
    const float* __restrict__ ftab, float* __restrict__ out) {
    __shared__ __align__(16) char sm[51200];
    float* P = (float*)(sm + 49152);
    const int tid = threadIdx.x;
    const int w = tid >> 6;        // wave 0..3
    const int lane = tid & 63;
    const int lg = lane >> 4;      // 0..3
    const int lr = lane & 15;      // 0..15
    const int mb = blockIdx.x * 64;
    const int wc = w * 48;         // this wave's tok/out col base

    // per-ct constants for this lane's cols
    float basev[3], lngv[3], lnbv[3];
    #pragma unroll
    for (int ct = 0; ct < 3; ++ct) {
        int n = wc + ct * 16 + lr;
        basev[ct] = gctx[n] + cons_b2[n];
        lngv[ct] = ln_g[n];
        lnbv[ct] = ln_b[n];
    }

    // ---- gathers -> acc2 (tok) in MFMA C-layout: row rt*16+lg*4+r, col wc+ct*16+lr
    f32x4 acc2[4][3];
    #pragma unroll
    for (int rt = 0; rt < 4; ++rt) {
        #pragma unroll
        for (int r = 0; r < 4; ++r) {
            int M = mb + rt * 16 + lg * 4 + r;
            uint2 k2 = pk[M];
            const float* p0 = piece + (k2.x & 0xffu) * 192;
            const float* p1 = piece + ((k2.x >> 8) & 0xffu) * 192;
            const float* p2 = sqe + ((k2.x >> 16) & 0xffu) * 192;
            const float* p3 = sqe + (k2.x >> 24) * 192;
            const float* p4 = kinde + (k2.y & 0xffu) * 192;
            const float* p5 = promoe + ((k2.y >> 8) & 0xffu) * 192;
            const float* p6 = metae + ((k2.y >> 16) & 0xffu) * 192;
            const float* p7 = ftab + (k2.y >> 24) * 192;
            #pragma unroll
            for (int ct = 0; ct < 3; ++ct) {
                int n = wc + ct * 16 + lr;
                acc2[rt][ct][r] = basev[ct] + p0[n] + p1[n] + p2[n] + p3[n]
                                + p4[n] + p5[n] + p6[n] + p7[n];
            }
        }
    }

    // ---- C1: h1 = gelu(cons @ W1 + b1); wave w produces h1 cols [w*96, w*96+96)
    bf16x8 af[4];
    #pragma unroll
    for (int rt = 0; rt < 4; ++rt) {
        int M = mb + rt * 16 + lr;
        #pragma unroll
        for (int i = 0; i < 8; ++i) {
            int k = lg * 8 + i;
            float v = (k < 12) ? cons[M * 12 + k] : 0.0f;
            af[rt][i] = (__bf16)v;
        }
    }
    #pragma unroll
    for (int hh = 0; hh < 2; ++hh) {
        f32x4 acc1[4][3];
        #pragma unroll
        for (int ct = 0; ct < 3; ++ct) {
            int n0 = w * 96 + hh * 48 + ct * 16;
            float b1v = cons_b1[n0 + lr];
            bf16x8 bf = *(const bf16x8*)(cW1t + (n0 + lr) * 32 + lg * 8);
            #pragma unroll
            for (int rt = 0; rt < 4; ++rt)
                acc1[rt][ct] = __builtin_amdgcn_mfma_f32_16x16x32_bf16(af[rt], bf, splat4(b1v), 0, 0, 0);
        }
        #pragma unroll
        for (int rt = 0; rt < 4; ++rt)
            #pragma unroll
            for (int ct = 0; ct < 3; ++ct)
                #pragma unroll
                for (int r = 0; r < 4; ++r) {
                    int row = rt * 16 + lg * 4 + r;
                    int col = w * 96 + hh * 48 + ct * 16 + lr;
                    *(__bf16*)(sm + ((row * 768 + 2 * col) ^ ((row & 7) << 4))) =
                        (__bf16)gelu_fast(acc1[rt][ct][r]);
                }
    }
    __syncthreads();  // h1 complete

    // ---- C2: tok += h1 @ cons_W2 (K=384)
    #pragma unroll
    for (int ks = 0; ks < 12; ++ks) {
        bf16x8 a[4], b[3];
        #pragma unroll
        for (int rt = 0; rt < 4; ++rt) {
            int row = rt * 16 + lr;
            a[rt] = *(const bf16x8*)(sm + ((row * 768 + ks * 64 + lg * 16) ^ ((row & 7) << 4)));
        }
        #pragma unroll
        for (int ct = 0; ct < 3; ++ct)
            b[ct] = *(const bf16x8*)(cW2t + (wc + ct * 16 + lr) * 384 + ks * 32 + lg * 8);
        #pragma unroll
        for (int rt = 0; rt < 4; ++rt)
            #pragma unroll
            for (int ct = 0; ct < 3; ++ct)
                acc2[rt][ct] = __builtin_amdgcn_mfma_f32_16x16x32_bf16(a[rt], b[ct], acc2[rt][ct], 0, 0, 0);
    }

    // ---- LN partials: per-row (s, s2) over this wave's 48 cols, butterfly over lr
    #pragma unroll
    for (int rt = 0; rt < 4; ++rt) {
        #pragma unroll
        for (int r = 0; r < 4; ++r) {
            float v0 = acc2[rt][0][r], v1 = acc2[rt][1][r], v2 = acc2[rt][2][r];
            float s = v0 + v1 + v2;
            float s2 = v0 * v0 + v1 * v1 + v2 * v2;
            s += __shfl_xor(s, 1); s2 += __shfl_xor(s2, 1);
            s += __shfl_xor(s, 2); s2 += __shfl_xor(s2, 2);
            s += __shfl_xor(s, 4); s2 += __shfl_xor(s2, 4);
            s += __shfl_xor(s, 8); s2 += __shfl_xor(s2, 8);
            if (lr == 0) {
                int row = rt * 16 + lg * 4 + r;
                f32x2 pv; pv[0] = s; pv[1] = s2;
                *(f32x2*)(P + row * 8 + w * 2) = pv;
            }
        }
    }
    __syncthreads();  // partials visible; all h1 reads done (region A reusable)

    // ---- LN finalize -> x bf16 into region A [64][192]
    #pragma unroll
    for (int rt = 0; rt < 4; ++rt) {
        #pragma unroll
        for (int r = 0; r < 4; ++r) {
            int row = rt * 16 + lg * 4 + r;
            f32x4 pa = *(const f32x4*)(P + row * 8);
            f32x4 pb = *(const f32x4*)(P + row * 8 + 4);
            float s = pa[0] + pa[2] + pb[0] + pb[2];
            float s2 = pa[1] + pa[3] + pb[1] + pb[3];
            float mu = s * (1.0f / 192.0f);
            float var = s2 * (1.0f / 192.0f) - mu * mu;
            float inv = rsqrtf(var + 1e-5f);
            #pragma unroll
            for (int ct = 0; ct < 3; ++ct) {
                int n = wc + ct * 16 + lr;
                float xv = (acc2[rt][ct][r] - mu) * inv * lngv[ct] + lnbv[ct];
                *(__bf16*)(sm + ((row * 384 + 2 * n) ^ ((row & 7) << 4))) = (__bf16)xv;
            }
        }
    }
    __syncthreads();  // x ready

    // ---- C3/C4 in halves over H=384; acc4 accumulates across halves
    f32x4 acc4[4][3];
    #pragma unroll
    for (int ct = 0; ct < 3; ++ct) {
        float b2v = out_b2[wc + ct * 16 + lr];
        #pragma unroll
        for (int rt = 0; rt < 4; ++rt) acc4[rt][ct] = splat4(b2v);
    }
    #pragma unroll
    for (int hh = 0; hh < 2; ++hh) {
        // C3: h2half = gelu(x @ oW1[:, hh*192 + ...]); wave w cols hh*192 + wc + ct*16
        f32x4 acc3[4][3];
        #pragma unroll
        for (int ct = 0; ct < 3; ++ct) {
            float b1v = out_b1[hh * 192 + wc + ct * 16 + lr];
            #pragma unroll
            for (int rt = 0; rt < 4; ++rt) acc3[rt][ct] = splat4(b1v);
        }
        #pragma unroll
        for (int ks = 0; ks < 6; ++ks) {
            bf16x8 a[4], b[3];
            #pragma unroll
            for (int rt = 0; rt < 4; ++rt) {
                int row = rt * 16 + lr;
                a[rt] = *(const bf16x8*)(sm + ((row * 384 + ks * 64 + lg * 16) ^ ((row & 7) << 4)));
            }
            #pragma unroll
            for (int ct = 0; ct < 3; ++ct) {
                int tt = hh * 12 + w * 3 + ct;
                b[ct] = *(const bf16x8*)(oW1t + (tt * 16 + lr) * 192 + ks * 32 + lg * 8);
            }
            #pragma unroll
            for (int rt = 0; rt < 4; ++rt)
                #pragma unroll
                for (int ct = 0; ct < 3; ++ct)
                    acc3[rt][ct] = __builtin_amdgcn_mfma_f32_16x16x32_bf16(a[rt], b[ct], acc3[rt][ct], 0, 0, 0);
        }
        #pragma unroll
        for (int rt = 0; rt < 4; ++rt)
            #pragma unroll
            for (int ct = 0; ct < 3; ++ct)
                #pragma unroll
                for (int r = 0; r < 4; ++r) {
                    int row = rt * 16 + lg * 4 + r;
                    int c = wc + ct * 16 + lr;
                    *(__bf16*)(sm + 24576 + ((row * 384 + 2 * c) ^ ((row & 7) << 4))) =
                        (__bf16)gelu_fast(acc3[rt][ct][r]);
                }
        __syncthreads();  // h2half ready
        // C4 partial: out += h2half @ oW2[hh*192 + ...]
        #pragma unroll
        for (int ks = 0; ks < 6; ++ks) {
            bf16x8 a[4], b[3];
            #pragma unroll
            for (int rt = 0; rt < 4; ++rt) {
                int row = rt * 16 + lr;
                a[rt] = *(const bf16x8*)(sm + 24576 + ((row * 384 + ks * 64 + lg * 16) ^ ((row & 7) << 4)));
            }
            #pragma unroll
            for (int ct = 0; ct < 3; ++ct) {
                int tt = w * 3 + ct;
                b[ct] = *(const bf16x8*)(oW2t + (tt * 16 + lr) * 384 + hh * 192 + ks * 32 + lg * 8);
            }
            #pragma unroll
            for (int rt = 0; rt < 4; ++rt)
                #pragma unroll
                for (int ct = 0; ct < 3; ++ct)
                    acc4[rt][ct] = __builtin_amdgcn_mfma_f32_16x16x32_bf16(a[rt], b[ct], acc4[rt][ct], 0, 0, 0);
        }
        if (hh == 0) __syncthreads();  // region B reads done before overwrite
    }

    // ---- store
    #pragma unroll
    for (int rt = 0; rt < 4; ++rt)
        #pragma unroll
        for (int ct = 0; ct < 3; ++ct)
            #pragma unroll
            for (int r = 0; r < 4; ++r)
                out[(mb + rt * 16 + lg * 4 + r) * 192 + wc + ct * 16 + lr] = acc4[rt][ct][r];
}

extern "C" void kernel_launch(void* const* d_in, const int* in_sizes, int n_in,
                              void* d_out, int out_size, void* d_ws, size_t ws_size,
                              hipStream_t stream) {
    const float* flags  = (const float*)d_in[0];
    const float* cons   = (const float*)d_in[1];
    const int* from_sq  = (const int*)d_in[2];
    const int* to_sq    = (const int*)d_in[3];
    const int* kind_id  = (const int*)d_in[4];
    const int* promo_id = (const int*)d_in[5];
    const int* meta_id  = (const int*)d_in[6];
    const int* mover    = (const int*)d_in[7];
    const int* target   = (const int*)d_in[8];
    const float* gctx   = (const float*)d_in[9];
    const float* piece  = (const float*)d_in[10];
    const float* sqe    = (const float*)d_in[11];
    const float* kinde  = (const float*)d_in[12];
    const float* promoe = (const float*)d_in[13];
    const float* metae  = (const float*)d_in[14];
    const float* fW1    = (const float*)d_in[15];
    const float* fb1    = (const float*)d_in[16];
    const float* fW2    = (const float*)d_in[17];
    const float* fb2    = (const float*)d_in[18];
    const float* cW1    = (const float*)d_in[19];
    const float* cb1    = (const float*)d_in[20];
    const float* cW2    = (const float*)d_in[21];
    const float* cb2    = (const float*)d_in[22];
    const float* lng    = (const float*)d_in[23];
    const float* lnb    = (const float*)d_in[24];
    const float* oW1    = (const float*)d_in[25];
    const float* ob1    = (const float*)d_in[26];
    const float* oW2    = (const float*)d_in[27];
    const float* ob2    = (const float*)d_in[28];
    float* out = (float*)d_out;
    int N = in_sizes[2];

    __bf16* ws = (__bf16*)d_ws;
    const __bf16* cW1t = ws;
    const __bf16* cW2t = ws + 12288;
    const __bf16* oW1t = ws + 86016;
    const __bf16* oW2t = ws + 159744;
    float* ftab = (float*)(ws + 233472);
    uint2* pkbuf = (uint2*)((char*)d_ws + 860160);

    prep_w<<<912, 256, 0, stream>>>(cW1, cW2, oW1, oW2, ws);
    prep_ft<<<128, 192, 0, stream>>>(fW1, fb1, fW2, fb2, ftab);
    prep_pack<<<(N + 255) / 256, 256, 0, stream>>>(flags, from_sq, to_sq, kind_id, promo_id,
                                                   meta_id, mover, target, pkbuf, N);
    me_main<<<N / 64, 256, 0, stream>>>(cons, pkbuf, gctx, piece, sqe, kinde, promoe, metae,
                                        cb1, cb2, lng, lnb, ob1, ob2,
                                        cW1t, cW2t, oW1t, oW2t, ftab, out);
}

// Round 4
// 950.391 us; speedup vs baseline: 2.0207x; 1.2865x over previous
//
#include <hip/hip_runtime.h>

#define DI __device__ __forceinline__

typedef __bf16 bf16x8 __attribute__((ext_vector_type(8)));
typedef float  f32x4  __attribute__((ext_vector_type(4)));
typedef float  f32x2  __attribute__((ext_vector_type(2)));

DI f32x4 splat4(float b) { f32x4 v; v[0] = b; v[1] = b; v[2] = b; v[3] = b; return v; }

// tanh-form GELU: gelu(x) = x / (1 + exp(-2u)), u = 0.79788456(x + 0.044715x^3)
DI float gelu_fast(float x) {
    float x3 = x * x * x;
    float z = -1.5957691216057308f * fmaf(0.044715f, x3, x);
    float e = __expf(z);
    return __fdividef(x, 1.0f + e);
}

// ---------------- prep: transpose weights to bf16 Bt[n][k] layouts ----------------
// ws (bf16 units): [0,12288) cons_W1t [384][32] (K padded 12->32)
//                  [12288,86016) cons_W2t [192][384]
//                  [86016,159744) out_W1t [384][192]
//                  [159744,233472) out_W2t [192][384]
// then ftab f32[128*192] at bf16-offset 233472 (byte 466944)
// then packed uint2[N] at byte 860160
__global__ void prep_w(const float* __restrict__ cW1, const float* __restrict__ cW2,
                       const float* __restrict__ oW1, const float* __restrict__ oW2,
                       __bf16* __restrict__ ws) {
    int id = blockIdx.x * 256 + threadIdx.x;
    if (id < 12288) {
        int n = id >> 5, k = id & 31;
        ws[id] = (k < 12) ? (__bf16)cW1[k * 384 + n] : (__bf16)0.0f;
    } else if (id < 86016) {
        int t = id - 12288;
        int n = t / 384, k = t % 384;
        ws[id] = (__bf16)cW2[k * 192 + n];
    } else if (id < 159744) {
        int t = id - 86016;
        int n = t / 192, k = t % 192;
        ws[id] = (__bf16)oW1[k * 384 + n];
    } else if (id < 233472) {
        int t = id - 159744;
        int n = t / 384, k = t % 384;
        ws[id] = (__bf16)oW2[k * 192 + n];
    }
}

// flag projection table: 128 combos x 192, exact erf GELU, f32
__global__ void prep_ft(const float* __restrict__ W1, const float* __restrict__ b1,
                        const float* __restrict__ W2, const float* __restrict__ b2,
                        float* __restrict__ ftab) {
    __shared__ float h[384];
    int c = blockIdx.x;
    int tid = threadIdx.x;  // 0..191
    #pragma unroll
    for (int half = 0; half < 2; ++half) {
        int j = tid + half * 192;
        float v = b1[j];
        #pragma unroll
        for (int i = 0; i < 7; ++i)
            if (c & (1 << i)) v += W1[i * 384 + j];
        h[j] = 0.5f * v * (1.0f + erff(v * 0.70710678118654752f));
    }
    __syncthreads();
    float acc = b2[tid];
    for (int j = 0; j < 384; ++j)
        acc += h[j] * W2[j * 192 + tid];
    ftab[c * 192 + tid] = acc;
}

// pack 6 indices + flag-code into one uint2 per move
__global__ void prep_pack(const float* __restrict__ flags,
                          const int* __restrict__ from_sq, const int* __restrict__ to_sq,
                          const int* __restrict__ kind_id, const int* __restrict__ promo_id,
                          const int* __restrict__ meta_id, const int* __restrict__ mover,
                          const int* __restrict__ target, uint2* __restrict__ pk, int N) {
    int t = blockIdx.x * 256 + threadIdx.x;
    if (t >= N) return;
    unsigned fc = 0;
    #pragma unroll
    for (int i = 0; i < 7; ++i) fc |= (flags[t * 7 + i] > 0.5f) ? (1u << i) : 0u;
    unsigned a = (unsigned)mover[t] | ((unsigned)target[t] << 8) |
                 ((unsigned)from_sq[t] << 16) | ((unsigned)to_sq[t] << 24);
    unsigned b = (unsigned)kind_id[t] | ((unsigned)promo_id[t] << 8) |
                 ((unsigned)meta_id[t] << 16) | (fc << 24);
    uint2 v; v.x = a; v.y = b;
    pk[t] = v;
}

// ---------------- fused main kernel: 4 waves cooperate on 64 moves ----------------
// wave w owns a 48-col slice; intermediates shared in LDS.
// LDS: [0,24576) region A: h1 cols 0..383 rows interleaved (h1 [64][384] spans A+B), later x[64][192]
//      [24576,49152) region B: later h2-half [64][192]
//      [49152,51200) region P: LN partials [64 rows][4 waves][2] f32
// __launch_bounds__(256,2): cap 256 VGPR — round-3's (256,3) capped at 84 VGPR and
// spilled all accumulators to scratch (1.6 GB of spill traffic, 9x output WRITE_SIZE).
__global__ __launch_bounds__(256, 2) void me_main(
    const float* __restrict__ cons, const uint2* __restrict__ pk,
    const float* __restrict__ gctx, const float* __restrict__ piece,
    const float* __restrict__ sqe, const float* __restrict__ kinde,
    const float* __restrict__ promoe, const float* __restrict__ metae,
    const float* __restrict__ cons_b1, const float* __restrict__ cons_b2,
    const float* __restrict__ ln_g, const float* __restrict__ ln_b,
    const float* __restrict__ out_b1, const float* __restrict__ out_b2,
    const __bf16* __restrict__ cW1t, const __bf16* __restrict__ cW2t,
    const __bf16* __restrict__ oW1t, const __bf16* __restrict__ oW2t,
    const float* __restrict__ ftab, float* __restrict__ out) {
    __shared__ __align__(16) char sm[51200];
    float* P = (float*)(sm + 49152);
    const int tid = threadIdx.x;
    const int w = tid >> 6;        // wave 0..3
    const int lane = tid & 63;
    const int lg = lane >> 4;      // 0..3
    const int lr = lane & 15;      // 0..15
    const int mb = blockIdx.x * 64;
    const int wc = w * 48;         // this wave's tok/out col base

    // ---- gathers -> acc2 (tok) in MFMA C-layout: row rt*16+lg*4+r, col wc+ct*16+lr
    float basev[3];
    #pragma unroll
    for (int ct = 0; ct < 3; ++ct) {
        int n = wc + ct * 16 + lr;
        basev[ct] = gctx[n] + cons_b2[n];
    }
    f32x4 acc2[4][3];
    #pragma unroll
    for (int rt = 0; rt < 4; ++rt) {
        #pragma unroll
        for (int r = 0; r < 4; ++r) {
            int M = mb + rt * 16 + lg * 4 + r;
            uint2 k2 = pk[M];
            const float* p0 = piece + (k2.x & 0xffu) * 192;
            const float* p1 = piece + ((k2.x >> 8) & 0xffu) * 192;
            const float* p2 = sqe + ((k2.x >> 16) & 0xffu) * 192;
            const float* p3 = sqe + (k2.x >> 24) * 192;
            const float* p4 = kinde + (k2.y & 0xffu) * 192;
            const float* p5 = promoe + ((k2.y >> 8) & 0xffu) * 192;
            const float* p6 = metae + ((k2.y >> 16) & 0xffu) * 192;
            const float* p7 = ftab + (k2.y >> 24) * 192;
            #pragma unroll
            for (int ct = 0; ct < 3; ++ct) {
                int n = wc + ct * 16 + lr;
                acc2[rt][ct][r] = basev[ct] + p0[n] + p1[n] + p2[n] + p3[n]
                                + p4[n] + p5[n] + p6[n] + p7[n];
            }
        }
    }

    // ---- C1: h1 = gelu(cons @ W1 + b1); wave w produces h1 cols [w*96, w*96+96)
    {
        bf16x8 af[4];
        #pragma unroll
        for (int rt = 0; rt < 4; ++rt) {
            int M = mb + rt * 16 + lr;
            #pragma unroll
            for (int i = 0; i < 8; ++i) {
                int k = lg * 8 + i;
                float v = (k < 12) ? cons[M * 12 + k] : 0.0f;
                af[rt][i] = (__bf16)v;
            }
        }
        #pragma unroll
        for (int hh = 0; hh < 2; ++hh) {
            f32x4 acc1[4][3];
            #pragma unroll
            for (int ct = 0; ct < 3; ++ct) {
                int n0 = w * 96 + hh * 48 + ct * 16;
                float b1v = cons_b1[n0 + lr];
                bf16x8 bf = *(const bf16x8*)(cW1t + (n0 + lr) * 32 + lg * 8);
                #pragma unroll
                for (int rt = 0; rt < 4; ++rt)
                    acc1[rt][ct] = __builtin_amdgcn_mfma_f32_16x16x32_bf16(af[rt], bf, splat4(b1v), 0, 0, 0);
            }
            #pragma unroll
            for (int rt = 0; rt < 4; ++rt)
                #pragma unroll
                for (int ct = 0; ct < 3; ++ct)
                    #pragma unroll
                    for (int r = 0; r < 4; ++r) {
                        int row = rt * 16 + lg * 4 + r;
                        int col = w * 96 + hh * 48 + ct * 16 + lr;
                        *(__bf16*)(sm + ((row * 768 + 2 * col) ^ ((row & 7) << 4))) =
                            (__bf16)gelu_fast(acc1[rt][ct][r]);
                    }
        }
    }
    __syncthreads();  // h1 complete

    // ---- C2: tok += h1 @ cons_W2 (K=384)
    #pragma unroll
    for (int ks = 0; ks < 12; ++ks) {
        bf16x8 a[4], b[3];
        #pragma unroll
        for (int rt = 0; rt < 4; ++rt) {
            int row = rt * 16 + lr;
            a[rt] = *(const bf16x8*)(sm + ((row * 768 + ks * 64 + lg * 16) ^ ((row & 7) << 4)));
        }
        #pragma unroll
        for (int ct = 0; ct < 3; ++ct)
            b[ct] = *(const bf16x8*)(cW2t + (wc + ct * 16 + lr) * 384 + ks * 32 + lg * 8);
        #pragma unroll
        for (int rt = 0; rt < 4; ++rt)
            #pragma unroll
            for (int ct = 0; ct < 3; ++ct)
                acc2[rt][ct] = __builtin_amdgcn_mfma_f32_16x16x32_bf16(a[rt], b[ct], acc2[rt][ct], 0, 0, 0);
    }

    // ---- LN partials: per-row (s, s2) over this wave's 48 cols, butterfly over lr
    #pragma unroll
    for (int rt = 0; rt < 4; ++rt) {
        #pragma unroll
        for (int r = 0; r < 4; ++r) {
            float v0 = acc2[rt][0][r], v1 = acc2[rt][1][r], v2 = acc2[rt][2][r];
            float s = v0 + v1 + v2;
            float s2 = v0 * v0 + v1 * v1 + v2 * v2;
            s += __shfl_xor(s, 1); s2 += __shfl_xor(s2, 1);
            s += __shfl_xor(s, 2); s2 += __shfl_xor(s2, 2);
            s += __shfl_xor(s, 4); s2 += __shfl_xor(s2, 4);
            s += __shfl_xor(s, 8); s2 += __shfl_xor(s2, 8);
            if (lr == 0) {
                int row = rt * 16 + lg * 4 + r;
                f32x2 pv; pv[0] = s; pv[1] = s2;
                *(f32x2*)(P + row * 8 + w * 2) = pv;
            }
        }
    }
    __syncthreads();  // partials visible; all h1 reads done (region A reusable)

    // ---- LN finalize -> x bf16 into region A [64][192]
    {
        float lngv[3], lnbv[3];
        #pragma unroll
        for (int ct = 0; ct < 3; ++ct) {
            int n = wc + ct * 16 + lr;
            lngv[ct] = ln_g[n];
            lnbv[ct] = ln_b[n];
        }
        #pragma unroll
        for (int rt = 0; rt < 4; ++rt) {
            #pragma unroll
            for (int r = 0; r < 4; ++r) {
                int row = rt * 16 + lg * 4 + r;
                f32x4 pa = *(const f32x4*)(P + row * 8);
                f32x4 pb = *(const f32x4*)(P + row * 8 + 4);
                float s = pa[0] + pa[2] + pb[0] + pb[2];
                float s2 = pa[1] + pa[3] + pb[1] + pb[3];
                float mu = s * (1.0f / 192.0f);
                float var = s2 * (1.0f / 192.0f) - mu * mu;
                float inv = rsqrtf(var + 1e-5f);
                #pragma unroll
                for (int ct = 0; ct < 3; ++ct) {
                    int n = wc + ct * 16 + lr;
                    float xv = (acc2[rt][ct][r] - mu) * inv * lngv[ct] + lnbv[ct];
                    *(__bf16*)(sm + ((row * 384 + 2 * n) ^ ((row & 7) << 4))) = (__bf16)xv;
                }
            }
        }
    }
    __syncthreads();  // x ready

    // ---- C3/C4 in halves over H=384; acc4 accumulates across halves
    f32x4 acc4[4][3];
    #pragma unroll
    for (int ct = 0; ct < 3; ++ct) {
        float b2v = out_b2[wc + ct * 16 + lr];
        #pragma unroll
        for (int rt = 0; rt < 4; ++rt) acc4[rt][ct] = splat4(b2v);
    }
    #pragma unroll
    for (int hh = 0; hh < 2; ++hh) {
        // C3: h2half = gelu(x @ oW1[:, hh half]); wave w cols hh*192 + wc + ct*16
        f32x4 acc3[4][3];
        #pragma unroll
        for (int ct = 0; ct < 3; ++ct) {
            float b1v = out_b1[hh * 192 + wc + ct * 16 + lr];
            #pragma unroll
            for (int rt = 0; rt < 4; ++rt) acc3[rt][ct] = splat4(b1v);
        }
        #pragma unroll
        for (int ks = 0; ks < 6; ++ks) {
            bf16x8 a[4], b[3];
            #pragma unroll
            for (int rt = 0; rt < 4; ++rt) {
                int row = rt * 16 + lr;
                a[rt] = *(const bf16x8*)(sm + ((row * 384 + ks * 64 + lg * 16) ^ ((row & 7) << 4)));
            }
            #pragma unroll
            for (int ct = 0; ct < 3; ++ct) {
                int tt = hh * 12 + w * 3 + ct;
                b[ct] = *(const bf16x8*)(oW1t + (tt * 16 + lr) * 192 + ks * 32 + lg * 8);
            }
            #pragma unroll
            for (int rt = 0; rt < 4; ++rt)
                #pragma unroll
                for (int ct = 0; ct < 3; ++ct)
                    acc3[rt][ct] = __builtin_amdgcn_mfma_f32_16x16x32_bf16(a[rt], b[ct], acc3[rt][ct], 0, 0, 0);
        }
        #pragma unroll
        for (int rt = 0; rt < 4; ++rt)
            #pragma unroll
            for (int ct = 0; ct < 3; ++ct)
                #pragma unroll
                for (int r = 0; r < 4; ++r) {
                    int row = rt * 16 + lg * 4 + r;
                    int c = wc + ct * 16 + lr;
                    *(__bf16*)(sm + 24576 + ((row * 384 + 2 * c) ^ ((row & 7) << 4))) =
                        (__bf16)gelu_fast(acc3[rt][ct][r]);
                }
        __syncthreads();  // h2half ready
        // C4 partial: out += h2half @ oW2[hh half]
        #pragma unroll
        for (int ks = 0; ks < 6; ++ks) {
            bf16x8 a[4], b[3];
            #pragma unroll
            for (int rt = 0; rt < 4; ++rt) {
                int row = rt * 16 + lr;
                a[rt] = *(const bf16x8*)(sm + 24576 + ((row * 384 + ks * 64 + lg * 16) ^ ((row & 7) << 4)));
            }
            #pragma unroll
            for (int ct = 0; ct < 3; ++ct) {
                int tt = w * 3 + ct;
                b[ct] = *(const bf16x8*)(oW2t + (tt * 16 + lr) * 384 + hh * 192 + ks * 32 + lg * 8);
            }
            #pragma unroll
            for (int rt = 0; rt < 4; ++rt)
                #pragma unroll
                for (int ct = 0; ct < 3; ++ct)
                    acc4[rt][ct] = __builtin_amdgcn_mfma_f32_16x16x32_bf16(a[rt], b[ct], acc4[rt][ct], 0, 0, 0);
        }
        if (hh == 0) __syncthreads();  // region B reads done before overwrite
    }

    // ---- store
    #pragma unroll
    for (int rt = 0; rt < 4; ++rt)
        #pragma unroll
        for (int ct = 0; ct < 3; ++ct)
            #pragma unroll
            for (int r = 0; r < 4; ++r)
                out[(mb + rt * 16 + lg * 4 + r) * 192 + wc + ct * 16 + lr] = acc4[rt][ct][r];
}

extern "C" void kernel_launch(void* const* d_in, const int* in_sizes, int n_in,
                              void* d_out, int out_size, void* d_ws, size_t ws_size,
                              hipStream_t stream) {
    const float* flags  = (const float*)d_in[0];
    const float* cons   = (const float*)d_in[1];
    const int* from_sq  = (const int*)d_in[2];
    const int* to_sq    = (const int*)d_in[3];
    const int* kind_id  = (const int*)d_in[4];
    const int* promo_id = (const int*)d_in[5];
    const int* meta_id  = (const int*)d_in[6];
    const int* mover    = (const int*)d_in[7];
    const int* target   = (const int*)d_in[8];
    const float* gctx   = (const float*)d_in[9];
    const float* piece  = (const float*)d_in[10];
    const float* sqe    = (const float*)d_in[11];
    const float* kinde  = (const float*)d_in[12];
    const float* promoe = (const float*)d_in[13];
    const float* metae  = (const float*)d_in[14];
    const float* fW1    = (const float*)d_in[15];
    const float* fb1    = (const float*)d_in[16];
    const float* fW2    = (const float*)d_in[17];
    const float* fb2    = (const float*)d_in[18];
    const float* cW1    = (const float*)d_in[19];
    const float* cb1    = (const float*)d_in[20];
    const float* cW2    = (const float*)d_in[21];
    const float* cb2    = (const float*)d_in[22];
    const float* lng    = (const float*)d_in[23];
    const float* lnb    = (const float*)d_in[24];
    const float* oW1    = (const float*)d_in[25];
    const float* ob1    = (const float*)d_in[26];
    const float* oW2    = (const float*)d_in[27];
    const float* ob2    = (const float*)d_in[28];
    float* out = (float*)d_out;
    int N = in_sizes[2];

    __bf16* ws = (__bf16*)d_ws;
    const __bf16* cW1t = ws;
    const __bf16* cW2t = ws + 12288;
    const __bf16* oW1t = ws + 86016;
    const __bf16* oW2t = ws + 159744;
    float* ftab = (float*)(ws + 233472);
    uint2* pkbuf = (uint2*)((char*)d_ws + 860160);

    prep_w<<<912, 256, 0, stream>>>(cW1, cW2, oW1, oW2, ws);
    prep_ft<<<128, 192, 0, stream>>>(fW1, fb1, fW2, fb2, ftab);
    prep_pack<<<(N + 255) / 256, 256, 0, stream>>>(flags, from_sq, to_sq, kind_id, promo_id,
                                                   meta_id, mover, target, pkbuf, N);
    me_main<<<N / 64, 256, 0, stream>>>(cons, pkbuf, gctx, piece, sqe, kinde, promoe, metae,
                                        cb1, cb2, lng, lnb, ob1, ob2,
                                        cW1t, cW2t, oW1t, oW2t, ftab, out);
}